// Round 1
// baseline (4355.710 us; speedup 1.0000x reference)
//
#include <hip/hip_runtime.h>

typedef __attribute__((ext_vector_type(8))) short bf16x8;
typedef __attribute__((ext_vector_type(4))) float f32x4;

#define NB 16
#define WID 56
#define HW 3136   // 56*56

// ---------- helpers ----------
__device__ __forceinline__ unsigned short f2bf(float f) {
  unsigned u = __float_as_uint(f);
  u = (u + 0x7fffu + ((u >> 16) & 1u)) >> 16;
  return (unsigned short)u;
}

// ---------- anchors ----------
// half-sizes after torchvision round(): ratios (0.5,1,2) x sizes (16,32,64)
__constant__ float cAW[9] = {11.f, 23.f, 45.f, 8.f, 16.f, 32.f, 6.f, 11.f, 23.f};
__constant__ float cAH[9] = {6.f, 11.f, 23.f, 8.f, 16.f, 32.f, 11.f, 23.f, 45.f};

__global__ void anchors_k(float* __restrict__ out) {
  int idx = blockIdx.x * 256 + threadIdx.x;
  if (idx >= HW * 9) return;
  int g = idx / 9, a = idx - g * 9;
  int y = g / WID, x = g - y * WID;
  float gx = x * 4.f, gy = y * 4.f;
  float4 v = make_float4(gx - cAW[a], gy - cAH[a], gx + cAW[a], gy + cAH[a]);
  *(float4*)(out + (size_t)idx * 4) = v;
}

// ---------- bilinear (align_corners=False, clamp edges; matches jax.image.resize upsample) ----------
__device__ __forceinline__ float bilerp(const float* __restrict__ plane, int Hin, float s, int h, int w) {
  float fy = ((float)h + 0.5f) * s - 0.5f;
  float fx = ((float)w + 0.5f) * s - 0.5f;
  float fy0 = floorf(fy), fx0 = floorf(fx);
  float ty = fy - fy0, tx = fx - fx0;
  int y0 = (int)fy0, x0 = (int)fx0;
  int y0c = min(max(y0, 0), Hin - 1);
  int y1c = min(max(y0 + 1, 0), Hin - 1);
  int x0c = min(max(x0, 0), Hin - 1);
  int x1c = min(max(x0 + 1, 0), Hin - 1);
  float v00 = plane[y0c * Hin + x0c], v01 = plane[y0c * Hin + x1c];
  float v10 = plane[y1c * Hin + x0c], v11 = plane[y1c * Hin + x1c];
  float a = v00 + tx * (v01 - v00);
  float b = v10 + tx * (v11 - v10);
  return a + ty * (b - a);
}

// X_cat NHWC bf16: [n][p][c], c in [0,1024)
__global__ void build_xcat(const float* __restrict__ fm0, const float* __restrict__ fm1,
                           const float* __restrict__ fm2, const float* __restrict__ fm3,
                           unsigned short* __restrict__ xcat) {
  long idx = (long)blockIdx.x * 256 + threadIdx.x;
  if (idx >= (long)NB * HW * 1024) return;
  int c = (int)(idx & 1023);
  long np = idx >> 10;
  int p = (int)(np % HW);
  int n = (int)(np / HW);
  int h = p / WID, w = p - (p / WID) * WID;
  float v;
  if (c < 256) {
    v = fm0[((long)(n * 256 + c)) * HW + p];
  } else if (c < 512) {
    const float* plane = fm1 + ((long)(n * 256 + (c - 256))) * 28 * 28;
    v = bilerp(plane, 28, 0.5f, h, w);
  } else if (c < 768) {
    const float* plane = fm2 + ((long)(n * 256 + (c - 512))) * 14 * 14;
    v = bilerp(plane, 14, 0.25f, h, w);
  } else {
    const float* plane = fm3 + ((long)(n * 256 + (c - 768))) * 7 * 7;
    v = bilerp(plane, 7, 0.125f, h, w);
  }
  xcat[idx] = f2bf(v);
}

// ---------- weight conversion ----------
// fuse_w (256,1024,1,1) fp32 -> bf16 [co][ci] (same order)
__global__ void fuse_w_k(const float* __restrict__ in, unsigned short* __restrict__ out) {
  int idx = blockIdx.x * 256 + threadIdx.x;
  if (idx >= 256 * 1024) return;
  out[idx] = f2bf(in[idx]);
}

// conv w (Co,256,3,3) fp32 -> bf16 [t][coPad][ci=256], zero-pad co >= Co
__global__ void conv_w_k(const float* __restrict__ in, unsigned short* __restrict__ out,
                         int Co, int CoPad) {
  int idx = blockIdx.x * 256 + threadIdx.x;
  int total = CoPad * 256 * 9;
  if (idx >= total) return;
  int ci = idx & 255;
  int co = (idx >> 8) % CoPad;
  int t = idx / (CoPad * 256);
  float v = (co < Co) ? in[(co * 256 + ci) * 9 + t] : 0.f;
  out[idx] = f2bf(v);
}

// ---------- conv via implicit GEMM over taps, MFMA 16x16x32 bf16 ----------
// act: NHWC bf16 [NB][HW][CIN]; wt: [NTAPS][CoPad][CIN] bf16
// mode 0: out_act NHWC bf16 [NB][HW][CoPad] (bias +, optional relu)
// mode 1: out_head fp32 [NB][HW][CoReal] (bias +, store only c < CoReal)
template <int CIN, int NTAPS>
__global__ __launch_bounds__(256) void conv_mfma(
    const unsigned short* __restrict__ act, const unsigned short* __restrict__ wt,
    const float* __restrict__ bias, unsigned short* __restrict__ out_act,
    float* __restrict__ out_head, int CoPad, int CoReal, int mode, int relu) {
  const int n = blockIdx.z;
  const int co_base = blockIdx.y * 64;
  const int sp_base = blockIdx.x * 64;
  const int tid = threadIdx.x;
  const int lane = tid & 63;
  const int wv = tid >> 6;
  const int wcoof = (wv >> 1) * 32, wspof = (wv & 1) * 32;
  const int colL = lane & 15;  // D col / B col / A row selector
  const int kgrp = lane >> 4;  // k group (8 consecutive k each)

  int p[2], hh[2], ww[2];
#pragma unroll
  for (int j = 0; j < 2; j++) {
    p[j] = sp_base + wspof + j * 16 + colL;
    hh[j] = p[j] / WID;
    ww[j] = p[j] - hh[j] * WID;
  }
  const int corow = co_base + wcoof + colL;
  const int actN = n * HW;

  f32x4 acc[2][2];
#pragma unroll
  for (int i = 0; i < 2; i++)
#pragma unroll
    for (int j = 0; j < 2; j++) acc[i][j] = (f32x4){0.f, 0.f, 0.f, 0.f};

#pragma unroll 1
  for (int t = 0; t < NTAPS; ++t) {
    const int dy = (NTAPS == 9) ? (t / 3 - 1) : 0;
    const int dx = (NTAPS == 9) ? (t - (t / 3) * 3 - 1) : 0;
    bool valid[2];
    int bofs[2];
#pragma unroll
    for (int j = 0; j < 2; j++) {
      int y = hh[j] + dy, x = ww[j] + dx;
      valid[j] = ((unsigned)y < (unsigned)WID) && ((unsigned)x < (unsigned)WID);
      bofs[j] = (actN + y * WID + x) * CIN + kgrp * 8;
    }
    const unsigned short* wbase = wt + (size_t)t * CoPad * CIN + (size_t)corow * CIN + kgrp * 8;
#pragma unroll 8
    for (int kk = 0; kk < CIN; kk += 32) {
      bf16x8 a0 = *(const bf16x8*)(wbase + kk);
      bf16x8 a1 = *(const bf16x8*)(wbase + 16 * CIN + kk);
      bf16x8 b0 = (bf16x8){0, 0, 0, 0, 0, 0, 0, 0};
      bf16x8 b1 = (bf16x8){0, 0, 0, 0, 0, 0, 0, 0};
      if (valid[0]) b0 = *(const bf16x8*)(act + bofs[0] + kk);
      if (valid[1]) b1 = *(const bf16x8*)(act + bofs[1] + kk);
      acc[0][0] = __builtin_amdgcn_mfma_f32_16x16x32_bf16(a0, b0, acc[0][0], 0, 0, 0);
      acc[0][1] = __builtin_amdgcn_mfma_f32_16x16x32_bf16(a0, b1, acc[0][1], 0, 0, 0);
      acc[1][0] = __builtin_amdgcn_mfma_f32_16x16x32_bf16(a1, b0, acc[1][0], 0, 0, 0);
      acc[1][1] = __builtin_amdgcn_mfma_f32_16x16x32_bf16(a1, b1, acc[1][1], 0, 0, 0);
    }
  }

  // epilogue: C/D layout col=lane&15, row=(lane>>4)*4+r
#pragma unroll
  for (int i = 0; i < 2; i++) {
    const int co0 = co_base + wcoof + i * 16 + kgrp * 4;
#pragma unroll
    for (int j = 0; j < 2; j++) {
      const int pp = p[j];
      float v[4];
#pragma unroll
      for (int r = 0; r < 4; r++) {
        float x = acc[i][j][r];
        int c = co0 + r;
        if (c < CoReal) x += bias[c];
        if (relu) x = fmaxf(x, 0.f);
        v[r] = x;
      }
      if (mode == 0) {
        ushort4 st = make_ushort4(f2bf(v[0]), f2bf(v[1]), f2bf(v[2]), f2bf(v[3]));
        *(ushort4*)(out_act + (size_t)(actN + pp) * CoPad + co0) = st;
      } else {
        float* dst = out_head + (size_t)(actN + pp) * CoReal;
#pragma unroll
        for (int r = 0; r < 4; r++) {
          int c = co0 + r;
          if (c < CoReal) dst[c] = v[r];
        }
      }
    }
  }
}

// ---------- launch ----------
extern "C" void kernel_launch(void* const* d_in, const int* in_sizes, int n_in,
                              void* d_out, int out_size, void* d_ws, size_t ws_size,
                              hipStream_t stream) {
  const float* fm0 = (const float*)d_in[0];
  const float* fm1 = (const float*)d_in[1];
  const float* fm2 = (const float*)d_in[2];
  const float* fm3 = (const float*)d_in[3];
  const float* fuse_w = (const float*)d_in[4];
  const float* fuse_b = (const float*)d_in[5];
  const float* cls_w = (const float*)d_in[6];
  const float* cls_b = (const float*)d_in[7];
  const float* cls_hw = (const float*)d_in[8];
  const float* cls_hb = (const float*)d_in[9];
  const float* reg_w = (const float*)d_in[10];
  const float* reg_b = (const float*)d_in[11];
  const float* reg_hw = (const float*)d_in[12];
  const float* reg_hb = (const float*)d_in[13];
  float* out = (float*)d_out;

  const size_t CLS_OFF = 0;
  const size_t REG_OFF = (size_t)NB * HW * 9 * 10;               // 4,515,840
  const size_t ANC_OFF = REG_OFF + (size_t)NB * HW * 9 * 4;      // 6,322,176

  char* ws = (char*)d_ws;
  const size_t XCAT_B = (size_t)NB * HW * 1024 * 2;  // 102,760,448
  const size_t ACT_B = (size_t)NB * HW * 256 * 2;    // 25,690,112
  unsigned short* xcat = (unsigned short*)ws;
  unsigned short* actA = (unsigned short*)ws;             // overlays xcat (dead after fuse)
  unsigned short* actB = (unsigned short*)(ws + ACT_B);
  unsigned short* fused = (unsigned short*)(ws + XCAT_B);
  char* wp = ws + XCAT_B + ACT_B;
  unsigned short* Wfuse = (unsigned short*)wp;
  wp += (size_t)256 * 1024 * 2;
  const size_t WL_B = (size_t)9 * 256 * 256 * 2;  // 1,179,648
  unsigned short* Wcls[4];
  for (int i = 0; i < 4; i++) { Wcls[i] = (unsigned short*)wp; wp += WL_B; }
  unsigned short* Wreg[4];
  for (int i = 0; i < 4; i++) { Wreg[i] = (unsigned short*)wp; wp += WL_B; }
  unsigned short* Wch = (unsigned short*)wp;  // [9][128][256]
  wp += (size_t)9 * 128 * 256 * 2;
  unsigned short* Wrh = (unsigned short*)wp;  // [9][64][256]
  wp += (size_t)9 * 64 * 256 * 2;

  // anchors
  anchors_k<<<dim3((HW * 9 + 255) / 256), 256, 0, stream>>>(out + ANC_OFF);

  // weight conversions
  fuse_w_k<<<dim3((256 * 1024) / 256), 256, 0, stream>>>(fuse_w, Wfuse);
  for (int i = 0; i < 4; i++) {
    conv_w_k<<<dim3((9 * 256 * 256) / 256), 256, 0, stream>>>(cls_w + (size_t)i * 589824, Wcls[i], 256, 256);
    conv_w_k<<<dim3((9 * 256 * 256) / 256), 256, 0, stream>>>(reg_w + (size_t)i * 589824, Wreg[i], 256, 256);
  }
  conv_w_k<<<dim3((9 * 128 * 256) / 256), 256, 0, stream>>>(cls_hw, Wch, 90, 128);
  conv_w_k<<<dim3((9 * 64 * 256) / 256), 256, 0, stream>>>(reg_hw, Wrh, 36, 64);

  // concat input (NHWC bf16) with on-the-fly bilinear upsample
  build_xcat<<<dim3((unsigned)(((long)NB * HW * 1024) / 256)), 256, 0, stream>>>(fm0, fm1, fm2, fm3, xcat);

  // fuse 1x1: K=1024 GEMM
  conv_mfma<1024, 1><<<dim3(49, 4, NB), 256, 0, stream>>>(xcat, Wfuse, fuse_b, fused, nullptr, 256, 256, 0, 0);

  // cls subnet
  conv_mfma<256, 9><<<dim3(49, 4, NB), 256, 0, stream>>>(fused, Wcls[0], cls_b + 0, actA, nullptr, 256, 256, 0, 1);
  conv_mfma<256, 9><<<dim3(49, 4, NB), 256, 0, stream>>>(actA, Wcls[1], cls_b + 256, actB, nullptr, 256, 256, 0, 1);
  conv_mfma<256, 9><<<dim3(49, 4, NB), 256, 0, stream>>>(actB, Wcls[2], cls_b + 512, actA, nullptr, 256, 256, 0, 1);
  conv_mfma<256, 9><<<dim3(49, 4, NB), 256, 0, stream>>>(actA, Wcls[3], cls_b + 768, actB, nullptr, 256, 256, 0, 1);
  conv_mfma<256, 9><<<dim3(49, 2, NB), 256, 0, stream>>>(actB, Wch, cls_hb, nullptr, out + CLS_OFF, 128, 90, 1, 0);

  // reg subnet
  conv_mfma<256, 9><<<dim3(49, 4, NB), 256, 0, stream>>>(fused, Wreg[0], reg_b + 0, actA, nullptr, 256, 256, 0, 1);
  conv_mfma<256, 9><<<dim3(49, 4, NB), 256, 0, stream>>>(actA, Wreg[1], reg_b + 256, actB, nullptr, 256, 256, 0, 1);
  conv_mfma<256, 9><<<dim3(49, 4, NB), 256, 0, stream>>>(actB, Wreg[2], reg_b + 512, actA, nullptr, 256, 256, 0, 1);
  conv_mfma<256, 9><<<dim3(49, 4, NB), 256, 0, stream>>>(actA, Wreg[3], reg_b + 768, actB, nullptr, 256, 256, 0, 1);
  conv_mfma<256, 9><<<dim3(49, 1, NB), 256, 0, stream>>>(actB, Wrh, reg_hb, nullptr, out + REG_OFF, 64, 36, 1, 0);
}

// Round 2
// 3391.727 us; speedup vs baseline: 1.2842x; 1.2842x over previous
//
#include <hip/hip_runtime.h>

typedef __attribute__((ext_vector_type(8))) short bf16x8;
typedef __attribute__((ext_vector_type(4))) float f32x4;

#define NB 16
#define WID 56
#define HW 3136    // 56*56
#define PW 58      // padded row width
#define NSTR 3520  // per-n position stride in padded act buffers
#define PBASE 64   // plane offset (positions) within per-n region
#define HALO 59    // max |dy*58+dx|

// ---------- helpers ----------
__device__ __forceinline__ unsigned short f2bf(float f) {
  unsigned u = __float_as_uint(f);
  u = (u + 0x7fffu + ((u >> 16) & 1u)) >> 16;
  return (unsigned short)u;
}

// ---------- anchors ----------
__constant__ float cAW[9] = {11.f, 23.f, 45.f, 8.f, 16.f, 32.f, 6.f, 11.f, 23.f};
__constant__ float cAH[9] = {6.f, 11.f, 23.f, 8.f, 16.f, 32.f, 11.f, 23.f, 45.f};

__global__ void anchors_k(float* __restrict__ out) {
  int idx = blockIdx.x * 256 + threadIdx.x;
  if (idx >= HW * 9) return;
  int g = idx / 9, a = idx - g * 9;
  int y = g / WID, x = g - y * WID;
  float gx = x * 4.f, gy = y * 4.f;
  float4 v = make_float4(gx - cAW[a], gy - cAH[a], gx + cAW[a], gy + cAH[a]);
  *(float4*)(out + (size_t)idx * 4) = v;
}

// ---------- bilinear ----------
__device__ __forceinline__ float bilerp(const float* __restrict__ plane, int Hin, float s, int h, int w) {
  float fy = ((float)h + 0.5f) * s - 0.5f;
  float fx = ((float)w + 0.5f) * s - 0.5f;
  float fy0 = floorf(fy), fx0 = floorf(fx);
  float ty = fy - fy0, tx = fx - fx0;
  int y0 = (int)fy0, x0 = (int)fx0;
  int y0c = min(max(y0, 0), Hin - 1);
  int y1c = min(max(y0 + 1, 0), Hin - 1);
  int x0c = min(max(x0, 0), Hin - 1);
  int x1c = min(max(x0 + 1, 0), Hin - 1);
  float v00 = plane[y0c * Hin + x0c], v01 = plane[y0c * Hin + x1c];
  float v10 = plane[y1c * Hin + x0c], v11 = plane[y1c * Hin + x1c];
  float a = v00 + tx * (v01 - v00);
  float b = v10 + tx * (v11 - v10);
  return a + ty * (b - a);
}

// X_cat NHWC bf16: [n][p][c], c in [0,1024)
__global__ void build_xcat(const float* __restrict__ fm0, const float* __restrict__ fm1,
                           const float* __restrict__ fm2, const float* __restrict__ fm3,
                           unsigned short* __restrict__ xcat) {
  long idx = (long)blockIdx.x * 256 + threadIdx.x;
  if (idx >= (long)NB * HW * 1024) return;
  int c = (int)(idx & 1023);
  long np = idx >> 10;
  int p = (int)(np % HW);
  int n = (int)(np / HW);
  int h = p / WID, w = p - (p / WID) * WID;
  float v;
  if (c < 256) {
    v = fm0[((long)(n * 256 + c)) * HW + p];
  } else if (c < 512) {
    const float* plane = fm1 + ((long)(n * 256 + (c - 256))) * 28 * 28;
    v = bilerp(plane, 28, 0.5f, h, w);
  } else if (c < 768) {
    const float* plane = fm2 + ((long)(n * 256 + (c - 512))) * 14 * 14;
    v = bilerp(plane, 14, 0.25f, h, w);
  } else {
    const float* plane = fm3 + ((long)(n * 256 + (c - 768))) * 7 * 7;
    v = bilerp(plane, 7, 0.125f, h, w);
  }
  xcat[idx] = f2bf(v);
}

// ---------- weight conversion ----------
__global__ void fuse_w_k(const float* __restrict__ in, unsigned short* __restrict__ out) {
  int idx = blockIdx.x * 256 + threadIdx.x;
  if (idx >= 256 * 1024) return;
  out[idx] = f2bf(in[idx]);
}

// conv w (Co,256,3,3) fp32 -> bf16 [t][coPad][ci=256]
__global__ void conv_w_k(const float* __restrict__ in, unsigned short* __restrict__ out,
                         int Co, int CoPad) {
  int idx = blockIdx.x * 256 + threadIdx.x;
  int total = CoPad * 256 * 9;
  if (idx >= total) return;
  int ci = idx & 255;
  int co = (idx >> 8) % CoPad;
  int t = idx / (CoPad * 256);
  float v = (co < Co) ? in[(co * 256 + ci) * 9 + t] : 0.f;
  out[idx] = f2bf(v);
}

// ---------- conv: implicit GEMM, LDS-staged act footprint ----------
// MODE 0: padded in -> padded out (bf16, bias+relu)   [subnet layers]
// MODE 1: padded in -> flat fp32 out interior, c<CoReal  [heads]
// MODE 2: flat in (stride CIN) -> padded out (bf16, bias) [fuse 1x1]
template <int CIN, int NTAPS, int CO_TILE, int MODE>
__global__ __launch_bounds__(256, 3) void conv_mfma(
    const unsigned short* __restrict__ act, const unsigned short* __restrict__ wt,
    const float* __restrict__ bias, unsigned short* __restrict__ out_act,
    float* __restrict__ out_head, int CoReal) {
  constexpr int STILE = 64;
  constexpr int FOOT = (NTAPS == 9) ? (STILE + 2 * HALO) : STILE;  // 182 or 64
  constexpr int FROWS = (NTAPS == 9) ? 192 : 64;
  constexpr int ITERS = FROWS / 16;
  constexpr int HALVES = CIN / 128;
  constexpr int NFI = CO_TILE / 32;
  static_assert(CO_TILE % 32 == 0, "");

  __shared__ __align__(16) char smem[FROWS * 256];

  const int n = blockIdx.z;
  const int sp0 = blockIdx.x * STILE;
  const int tid = threadIdx.x;
  const int lane = tid & 63;
  const int colL = lane & 15;
  const int kgrp = lane >> 4;
  const int wv = tid >> 6;
  const int wco = wv & 1;
  const int wsp = wv >> 1;
  const int wcobase = wco * (CO_TILE / 2);

  f32x4 acc[NFI][2];
#pragma unroll
  for (int i = 0; i < NFI; i++)
#pragma unroll
    for (int j = 0; j < 2; j++) acc[i][j] = (f32x4){0.f, 0.f, 0.f, 0.f};

  // staging thread mapping: 16 positions x 16 chunks per iter
  const int spos = tid >> 4;
  const int schunk = tid & 15;
  const int sb0 = wsp * 32 + colL;

#pragma unroll 1
  for (int half = 0; half < HALVES; ++half) {
    __syncthreads();
#pragma unroll
    for (int it = 0; it < ITERS; ++it) {
      int pos = it * 16 + spos;
      int posc = (pos < FOOT) ? pos : (FOOT - 1);
      const unsigned short* g;
      if constexpr (MODE == 2) {
        int row = sp0 + posc;
        if (row > HW - 1) row = HW - 1;
        g = act + ((size_t)n * HW + row) * CIN + half * 128 + (size_t)((schunk ^ (posc & 15)) * 8);
      } else {
        g = act + ((size_t)n * NSTR + PBASE + sp0 - HALO + posc) * 256 + half * 128 +
            (size_t)((schunk ^ (posc & 15)) * 8);
      }
      char* l = smem + pos * 256 + schunk * 16;
      __builtin_amdgcn_global_load_lds((const __attribute__((address_space(1))) void*)g,
                                       (__attribute__((address_space(3))) void*)l, 16, 0, 0);
    }
    asm volatile("s_waitcnt vmcnt(0)" ::: "memory");
    __syncthreads();

    const unsigned short* whalf = wt + half * 128;
#pragma unroll 1
    for (int t = 0; t < NTAPS; ++t) {
      const int tapadd = (NTAPS == 9) ? ((t / 3) * PW + (t - (t / 3) * 3)) : 0;
      const unsigned short* wtap = whalf + (size_t)t * CO_TILE * CIN + (size_t)(wcobase + colL) * CIN;
#pragma unroll
      for (int kk = 0; kk < 4; ++kk) {
        bf16x8 a[NFI];
#pragma unroll
        for (int i = 0; i < NFI; ++i)
          a[i] = *(const bf16x8*)(wtap + (size_t)i * 16 * CIN + kk * 32 + kgrp * 8);
        bf16x8 b[2];
#pragma unroll
        for (int j = 0; j < 2; ++j) {
          int pl = sb0 + j * 16 + tapadd;
          int byte = pl * 256 + ((kk * 64 + kgrp * 16) ^ ((pl & 15) << 4));
          b[j] = *(const bf16x8*)(smem + byte);
        }
#pragma unroll
        for (int i = 0; i < NFI; ++i) {
          acc[i][0] = __builtin_amdgcn_mfma_f32_16x16x32_bf16(a[i], b[0], acc[i][0], 0, 0, 0);
          acc[i][1] = __builtin_amdgcn_mfma_f32_16x16x32_bf16(a[i], b[1], acc[i][1], 0, 0, 0);
        }
      }
    }
  }

  // epilogue: C/D col=lane&15 (spatial), row=(lane>>4)*4+r (co)
#pragma unroll
  for (int i = 0; i < NFI; ++i) {
    const int co0 = wcobase + i * 16 + kgrp * 4;
#pragma unroll
    for (int j = 0; j < 2; ++j) {
      const int s = wsp * 32 + j * 16 + colL;
      float v[4];
#pragma unroll
      for (int r = 0; r < 4; ++r) {
        float x = acc[i][j][r];
        int c = co0 + r;
        if (MODE != 1 || c < CoReal) x += bias[(MODE == 1 && c >= CoReal) ? 0 : c];
        if (MODE == 0) x = fmaxf(x, 0.f);
        v[r] = x;
      }
      if constexpr (MODE == 0) {
        const int pp = sp0 + s;
        int hp = pp / PW, wp_ = pp - hp * PW;
        bool inter = ((unsigned)(hp - 1) < 56u) && ((unsigned)(wp_ - 1) < 56u);
        ushort4 st;
        st.x = f2bf(inter ? v[0] : 0.f);
        st.y = f2bf(inter ? v[1] : 0.f);
        st.z = f2bf(inter ? v[2] : 0.f);
        st.w = f2bf(inter ? v[3] : 0.f);
        *(ushort4*)(out_act + ((size_t)n * NSTR + PBASE + pp) * 256 + co0) = st;
      } else if constexpr (MODE == 2) {
        const int p = sp0 + s;
        if (p < HW) {
          int h = p / WID, w = p - h * WID;
          int pp = (h + 1) * PW + (w + 1);
          ushort4 st;
          st.x = f2bf(v[0]); st.y = f2bf(v[1]); st.z = f2bf(v[2]); st.w = f2bf(v[3]);
          *(ushort4*)(out_act + ((size_t)n * NSTR + PBASE + pp) * 256 + co0) = st;
        }
      } else {
        const int pp = sp0 + s;
        int hp = pp / PW, wp_ = pp - hp * PW;
        if (((unsigned)(hp - 1) < 56u) && ((unsigned)(wp_ - 1) < 56u)) {
          int p = (hp - 1) * WID + (wp_ - 1);
          float* dst = out_head + ((size_t)n * HW + p) * CoReal;
#pragma unroll
          for (int r = 0; r < 4; ++r) {
            int c = co0 + r;
            if (c < CoReal) dst[c] = v[r];
          }
        }
      }
    }
  }
}

// ---------- launch ----------
extern "C" void kernel_launch(void* const* d_in, const int* in_sizes, int n_in,
                              void* d_out, int out_size, void* d_ws, size_t ws_size,
                              hipStream_t stream) {
  const float* fm0 = (const float*)d_in[0];
  const float* fm1 = (const float*)d_in[1];
  const float* fm2 = (const float*)d_in[2];
  const float* fm3 = (const float*)d_in[3];
  const float* fuse_w = (const float*)d_in[4];
  const float* fuse_b = (const float*)d_in[5];
  const float* cls_w = (const float*)d_in[6];
  const float* cls_b = (const float*)d_in[7];
  const float* cls_hw = (const float*)d_in[8];
  const float* cls_hb = (const float*)d_in[9];
  const float* reg_w = (const float*)d_in[10];
  const float* reg_b = (const float*)d_in[11];
  const float* reg_hw = (const float*)d_in[12];
  const float* reg_hb = (const float*)d_in[13];
  float* out = (float*)d_out;

  const size_t CLS_OFF = 0;
  const size_t REG_OFF = (size_t)NB * HW * 9 * 10;           // 4,515,840
  const size_t ANC_OFF = REG_OFF + (size_t)NB * HW * 9 * 4;  // 6,322,176

  char* ws = (char*)d_ws;
  const size_t ACTP_B = (size_t)NB * NSTR * 256 * 2;   // 28,835,840
  const size_t XCAT_B = (size_t)NB * HW * 1024 * 2;    // 102,760,448
  const size_t WL_B = (size_t)9 * 256 * 256 * 2;       // 1,179,648

  unsigned short* xcat = (unsigned short*)ws;
  unsigned short* actA = (unsigned short*)ws;                   // overlays xcat (dead after fuse)
  unsigned short* actB = (unsigned short*)(ws + ACTP_B);        // overlays xcat
  unsigned short* Wsub[8];
  for (int i = 0; i < 8; i++) Wsub[i] = (unsigned short*)(ws + 2 * ACTP_B + (size_t)i * WL_B);  // overlays xcat
  unsigned short* fusedB = (unsigned short*)(ws + XCAT_B);
  char* wp = ws + XCAT_B + ACTP_B;
  unsigned short* Wfuse = (unsigned short*)wp; wp += (size_t)256 * 1024 * 2;
  unsigned short* Wch = (unsigned short*)wp;   wp += (size_t)9 * 128 * 256 * 2;
  unsigned short* Wrh = (unsigned short*)wp;   wp += (size_t)9 * 64 * 256 * 2;

  // zero padded fuse-output buffer (borders + slack must be 0)
  hipMemsetAsync(fusedB, 0, ACTP_B, stream);

  anchors_k<<<dim3((HW * 9 + 255) / 256), 256, 0, stream>>>(out + ANC_OFF);
  fuse_w_k<<<dim3((256 * 1024) / 256), 256, 0, stream>>>(fuse_w, Wfuse);
  conv_w_k<<<dim3((9 * 128 * 256) / 256), 256, 0, stream>>>(cls_hw, Wch, 90, 128);
  conv_w_k<<<dim3((9 * 64 * 256) / 256), 256, 0, stream>>>(reg_hw, Wrh, 36, 64);

  build_xcat<<<dim3((unsigned)(((long)NB * HW * 1024) / 256)), 256, 0, stream>>>(fm0, fm1, fm2, fm3, xcat);

  // fuse 1x1 (flat in, padded out). xcat fully consumed after this.
  conv_mfma<1024, 1, 256, 2><<<dim3(49, 1, NB), 256, 0, stream>>>(xcat, Wfuse, fuse_b, fusedB, nullptr, 256);

  // subnet weights into (now dead) xcat region
  for (int i = 0; i < 4; i++)
    conv_w_k<<<dim3((9 * 256 * 256) / 256), 256, 0, stream>>>(cls_w + (size_t)i * 589824, Wsub[i], 256, 256);
  for (int i = 0; i < 4; i++)
    conv_w_k<<<dim3((9 * 256 * 256) / 256), 256, 0, stream>>>(reg_w + (size_t)i * 589824, Wsub[4 + i], 256, 256);

  // cls subnet
  conv_mfma<256, 9, 256, 0><<<dim3(53, 1, NB), 256, 0, stream>>>(fusedB, Wsub[0], cls_b + 0, actA, nullptr, 256);
  conv_mfma<256, 9, 256, 0><<<dim3(53, 1, NB), 256, 0, stream>>>(actA, Wsub[1], cls_b + 256, actB, nullptr, 256);
  conv_mfma<256, 9, 256, 0><<<dim3(53, 1, NB), 256, 0, stream>>>(actB, Wsub[2], cls_b + 512, actA, nullptr, 256);
  conv_mfma<256, 9, 256, 0><<<dim3(53, 1, NB), 256, 0, stream>>>(actA, Wsub[3], cls_b + 768, actB, nullptr, 256);
  conv_mfma<256, 9, 128, 1><<<dim3(53, 1, NB), 256, 0, stream>>>(actB, Wch, cls_hb, nullptr, out + CLS_OFF, 90);

  // reg subnet
  conv_mfma<256, 9, 256, 0><<<dim3(53, 1, NB), 256, 0, stream>>>(fusedB, Wsub[4], reg_b + 0, actA, nullptr, 256);
  conv_mfma<256, 9, 256, 0><<<dim3(53, 1, NB), 256, 0, stream>>>(actA, Wsub[5], reg_b + 256, actB, nullptr, 256);
  conv_mfma<256, 9, 256, 0><<<dim3(53, 1, NB), 256, 0, stream>>>(actB, Wsub[6], reg_b + 512, actA, nullptr, 256);
  conv_mfma<256, 9, 256, 0><<<dim3(53, 1, NB), 256, 0, stream>>>(actA, Wsub[7], reg_b + 768, actB, nullptr, 256);
  conv_mfma<256, 9, 64, 1><<<dim3(53, 1, NB), 256, 0, stream>>>(actB, Wrh, reg_hb, nullptr, out + REG_OFF, 36);
}

// Round 4
// 996.785 us; speedup vs baseline: 4.3698x; 3.4027x over previous
//
#include <hip/hip_runtime.h>

typedef __attribute__((ext_vector_type(8))) short bf16x8;
typedef __attribute__((ext_vector_type(4))) float f32x4;
typedef __attribute__((ext_vector_type(16))) float f32x16;

#define NB 16
#define WID 56
#define HW 3136    // 56*56
#define PW 58      // padded row width
#define NSTR 3520  // per-n position stride in padded act buffers
#define PBASE 64   // plane offset (positions) within per-n region
#define HALO 59    // max |dy*58+dx|

// ---------- helpers ----------
__device__ __forceinline__ unsigned short f2bf(float f) {
  unsigned u = __float_as_uint(f);
  u = (u + 0x7fffu + ((u >> 16) & 1u)) >> 16;
  return (unsigned short)u;
}
__device__ __forceinline__ float bf2f(unsigned short u) {
  return __uint_as_float(((unsigned)u) << 16);
}

// ---------- anchors ----------
__constant__ float cAW[9] = {11.f, 23.f, 45.f, 8.f, 16.f, 32.f, 6.f, 11.f, 23.f};
__constant__ float cAH[9] = {6.f, 11.f, 23.f, 8.f, 16.f, 32.f, 11.f, 23.f, 45.f};

__global__ void anchors_k(float* __restrict__ out) {
  int idx = blockIdx.x * 256 + threadIdx.x;
  if (idx >= HW * 9) return;
  int g = idx / 9, a = idx - g * 9;
  int y = g / WID, x = g - y * WID;
  float gx = x * 4.f, gy = y * 4.f;
  float4 v = make_float4(gx - cAW[a], gy - cAH[a], gx + cAW[a], gy + cAH[a]);
  *(float4*)(out + (size_t)idx * 4) = v;
}

// ---------- weight conversion ----------
// fuse_w (256,1024) fp32 -> bf16 same layout
__global__ void fuse_w_k(const float* __restrict__ in, unsigned short* __restrict__ out) {
  int idx = blockIdx.x * 256 + threadIdx.x;
  if (idx >= 256 * 1024) return;
  out[idx] = f2bf(in[idx]);
}

// conv w (Co,256,3,3) fp32 -> bf16 [t][coPad][ci=256]
__global__ void conv_w_k(const float* __restrict__ in, unsigned short* __restrict__ out,
                         int Co, int CoPad) {
  int idx = blockIdx.x * 256 + threadIdx.x;
  int total = CoPad * 256 * 9;
  if (idx >= total) return;
  int ci = idx & 255;
  int co = (idx >> 8) % CoPad;
  int t = idx / (CoPad * 256);
  float v = (co < Co) ? in[(co * 256 + ci) * 9 + t] : 0.f;
  out[idx] = f2bf(v);
}

// ---------- NCHW fp32 -> NHWC bf16 transpose ----------
__global__ __launch_bounds__(256) void nchw2nhwc(const float* __restrict__ in,
                                                 unsigned short* __restrict__ outb, int HWl) {
  __shared__ float tile[64][65];
  const int pb = blockIdx.x * 64;
  const int cb = blockIdx.y * 64;
  const int n = blockIdx.z;
  const int t = threadIdx.x;
  const int pl = t & 63;
#pragma unroll
  for (int i = 0; i < 16; ++i) {
    int cl = i * 4 + (t >> 6);
    int p = pb + pl;
    if (p >= HWl) p = HWl - 1;
    tile[cl][pl] = in[((size_t)n * 256 + cb + cl) * HWl + p];
  }
  __syncthreads();
  const int pl2 = t >> 4;         // 0..15
  const int cl2 = (t & 15) * 4;   // 0..60
#pragma unroll
  for (int i = 0; i < 4; ++i) {
    int pp = pb + i * 16 + pl2;
    if (pp < HWl) {
      ushort4 st;
      st.x = f2bf(tile[cl2 + 0][i * 16 + pl2]);
      st.y = f2bf(tile[cl2 + 1][i * 16 + pl2]);
      st.z = f2bf(tile[cl2 + 2][i * 16 + pl2]);
      st.w = f2bf(tile[cl2 + 3][i * 16 + pl2]);
      *(ushort4*)(outb + ((size_t)n * HWl + pp) * 256 + cb + cl2) = st;
    }
  }
}

// ---------- upsample-add combine: fused(padded) += U(y1)+U(y2)+U(y3) ----------
__device__ __forceinline__ void add_up(float* v, const unsigned short* __restrict__ y,
                                       int n, int S, float r, int h, int w, int c8) {
  float fy = ((float)h + 0.5f) * r - 0.5f;
  float fx = ((float)w + 0.5f) * r - 0.5f;
  float fyf = floorf(fy), fxf = floorf(fx);
  float ty = fy - fyf, tx = fx - fxf;
  int y0 = (int)fyf, x0 = (int)fxf;
  int y0c = min(max(y0, 0), S - 1), y1c = min(max(y0 + 1, 0), S - 1);
  int x0c = min(max(x0, 0), S - 1), x1c = min(max(x0 + 1, 0), S - 1);
  const unsigned short* b = y + (size_t)n * S * S * 256;
  bf16x8 a00 = *(const bf16x8*)(b + ((size_t)(y0c * S + x0c)) * 256 + c8);
  bf16x8 a01 = *(const bf16x8*)(b + ((size_t)(y0c * S + x1c)) * 256 + c8);
  bf16x8 a10 = *(const bf16x8*)(b + ((size_t)(y1c * S + x0c)) * 256 + c8);
  bf16x8 a11 = *(const bf16x8*)(b + ((size_t)(y1c * S + x1c)) * 256 + c8);
  float w00 = (1.f - ty) * (1.f - tx), w01 = (1.f - ty) * tx;
  float w10 = ty * (1.f - tx), w11 = ty * tx;
#pragma unroll
  for (int e = 0; e < 8; ++e) {
    v[e] += w00 * bf2f((unsigned short)a00[e]) + w01 * bf2f((unsigned short)a01[e]) +
            w10 * bf2f((unsigned short)a10[e]) + w11 * bf2f((unsigned short)a11[e]);
  }
}

__global__ __launch_bounds__(256) void combine_k(unsigned short* __restrict__ fused,
                                                 const unsigned short* __restrict__ y1,
                                                 const unsigned short* __restrict__ y2,
                                                 const unsigned short* __restrict__ y3) {
  int idx = blockIdx.x * 256 + threadIdx.x;  // [n][3136][32 octets]
  int c8 = (idx & 31) * 8;
  int np = idx >> 5;
  int p = np % HW;
  int n = np / HW;
  int h = p / WID, w = p - h * WID;
  size_t po = ((size_t)n * NSTR + PBASE + (h + 1) * PW + (w + 1)) * 256 + c8;
  bf16x8 f0 = *(bf16x8*)(fused + po);
  float v[8];
#pragma unroll
  for (int e = 0; e < 8; ++e) v[e] = bf2f((unsigned short)f0[e]);
  add_up(v, y1, n, 28, 0.5f, h, w, c8);
  add_up(v, y2, n, 14, 0.25f, h, w, c8);
  add_up(v, y3, n, 7, 0.125f, h, w, c8);
  bf16x8 st;
#pragma unroll
  for (int e = 0; e < 8; ++e) st[e] = (short)f2bf(v[e]);
  *(bf16x8*)(fused + po) = st;
}

// ---------- conv3: implicit GEMM, 32x32x16 MFMA, W+act both in LDS ----------
// Block: 128co x 256sp, 4 waves (wsp = wv&1 two sp-halves of 128, wco = wv>>1 two co-halves of 64).
// Wave tile: 64co x 128sp = 2 co-frags x 4 sp-frags of 32.
// act LDS: [8 k-slots][384 pos][16B] at 0 (48KB). W LDS: 2 x [8 slots][128 co][16B] at 49152.
// K-chain: 4 ci-quarters(64) x NTAPS taps x 4 k16.
// MODE 0: padded-in -> padded-out bf16, bias+relu (subnet)
// MODE 1: padded-in -> flat fp32 out, co<CoReal, bias (heads)
// MODE 2: flat-in[HWl][256] -> padded-out bf16, bias (fuse level 0)
// MODE 3: flat-in[HWl][256] -> flat-out bf16 [HWl][256], no bias (fuse levels 1-3)
template <int NTAPS, int MODE>
__global__ __launch_bounds__(256, 2) void conv3(
    const unsigned short* __restrict__ act, const unsigned short* __restrict__ wt,
    int wrs, int wts, const float* __restrict__ bias,
    unsigned short* __restrict__ out_bf, float* __restrict__ out_f32,
    int CoReal, int HWl) {
  __shared__ __align__(16) char smem[48 * 1024 + 2 * 16 * 1024];
  const int n = blockIdx.z;
  const int cb = blockIdx.y * 128;
  const int sp0 = blockIdx.x * 256;
  const int tid = threadIdx.x;
  const int lane = tid & 63;
  const int wv = tid >> 6;
  const int wsp = wv & 1;
  const int wco = wv >> 1;
  const int l31 = lane & 31;
  const int hh = lane >> 5;

  f32x16 acc[2][4];
#pragma unroll
  for (int i = 0; i < 2; ++i)
#pragma unroll
    for (int j = 0; j < 4; ++j)
#pragma unroll
      for (int r = 0; r < 16; ++r) acc[i][j][r] = 0.f;

  // ---- staging lambdas ----
  auto stage_act = [&](int q) {
    if constexpr (MODE <= 1) {
      const unsigned short* base =
          act + ((size_t)n * NSTR + PBASE + sp0 - HALO) * 256 + q * 64;
#pragma unroll
      for (int i = 0; i < 12; ++i) {
        int G = i * 256 + tid;
        int s = G / 384;
        int pos = G - s * 384;
        const unsigned short* g = base + (size_t)pos * 256 + s * 8;
        __builtin_amdgcn_global_load_lds((const __attribute__((address_space(1))) void*)g,
                                         (__attribute__((address_space(3))) void*)(smem + (size_t)G * 16),
                                         16, 0, 0);
      }
    } else {
#pragma unroll
      for (int i = 0; i < 8; ++i) {
        int G = i * 256 + tid;
        int s = G >> 8;
        int pos = G & 255;
        int row = sp0 + pos;
        if (row > HWl - 1) row = HWl - 1;
        const unsigned short* g = act + ((size_t)n * HWl + row) * 256 + q * 64 + s * 8;
        __builtin_amdgcn_global_load_lds((const __attribute__((address_space(1))) void*)g,
                                         (__attribute__((address_space(3))) void*)(smem + (size_t)s * 6144 + pos * 16),
                                         16, 0, 0);
      }
    }
  };

  auto stage_w = [&](int pair, int bufsel) {
    int q = pair / NTAPS;
    int t = pair - q * NTAPS;
    const unsigned short* base = wt + (size_t)t * wts + (size_t)cb * wrs + q * 64;
    char* wb = smem + 49152 + bufsel * 16384;
#pragma unroll
    for (int i = 0; i < 4; ++i) {
      int G = i * 256 + tid;
      int s = G >> 7, co = G & 127;
      const unsigned short* g = base + (size_t)co * wrs + s * 8;
      __builtin_amdgcn_global_load_lds((const __attribute__((address_space(1))) void*)g,
                                       (__attribute__((address_space(3))) void*)(wb + (size_t)G * 16),
                                       16, 0, 0);
    }
  };

  constexpr int TP = 4 * NTAPS;

  stage_act(0);
  stage_w(0, 0);
  asm volatile("s_waitcnt vmcnt(0)" ::: "memory");
  __syncthreads();

  const int abase0 = 49152 + (wco * 64 + l31) * 16 + hh * 2048;
  const int bpos0 = wsp * 128 + l31;

  int p = 0;
#pragma unroll 1
  for (int q = 0; q < 4; ++q) {
#pragma unroll 1
    for (int t = 0; t < NTAPS; ++t, ++p) {
      if (p + 1 < TP) stage_w(p + 1, (p + 1) & 1);
      const int tapadd = (NTAPS == 9) ? ((t / 3) * PW + (t - (t / 3) * 3)) : 0;
      const char* wbuf = smem + (p & 1) * 16384;
      const int bb = (bpos0 + tapadd) * 16 + hh * 6144;
#pragma unroll
      for (int kk = 0; kk < 4; ++kk) {
        bf16x8 a0 = *(const bf16x8*)(wbuf + abase0 + kk * 4096);
        bf16x8 a1 = *(const bf16x8*)(wbuf + abase0 + 512 + kk * 4096);
        bf16x8 b0 = *(const bf16x8*)(smem + bb + kk * 12288);
        bf16x8 b1 = *(const bf16x8*)(smem + bb + 512 + kk * 12288);
        bf16x8 b2 = *(const bf16x8*)(smem + bb + 1024 + kk * 12288);
        bf16x8 b3 = *(const bf16x8*)(smem + bb + 1536 + kk * 12288);
        acc[0][0] = __builtin_amdgcn_mfma_f32_32x32x16_bf16(a0, b0, acc[0][0], 0, 0, 0);
        acc[0][1] = __builtin_amdgcn_mfma_f32_32x32x16_bf16(a0, b1, acc[0][1], 0, 0, 0);
        acc[0][2] = __builtin_amdgcn_mfma_f32_32x32x16_bf16(a0, b2, acc[0][2], 0, 0, 0);
        acc[0][3] = __builtin_amdgcn_mfma_f32_32x32x16_bf16(a0, b3, acc[0][3], 0, 0, 0);
        acc[1][0] = __builtin_amdgcn_mfma_f32_32x32x16_bf16(a1, b0, acc[1][0], 0, 0, 0);
        acc[1][1] = __builtin_amdgcn_mfma_f32_32x32x16_bf16(a1, b1, acc[1][1], 0, 0, 0);
        acc[1][2] = __builtin_amdgcn_mfma_f32_32x32x16_bf16(a1, b2, acc[1][2], 0, 0, 0);
        acc[1][3] = __builtin_amdgcn_mfma_f32_32x32x16_bf16(a1, b3, acc[1][3], 0, 0, 0);
      }
      if (t == NTAPS - 1 && q < 3) {
        __syncthreads();
        stage_act(q + 1);
      }
      asm volatile("s_waitcnt vmcnt(0)" ::: "memory");
      __syncthreads();
    }
  }

  // ---- epilogue: D col = lane&31 (sp), row = (r&3)+8*(r>>2)+4*(lane>>5) (co) ----
  float4 biasv[2][4];
  if constexpr (MODE != 3) {
#pragma unroll
    for (int i = 0; i < 2; ++i)
#pragma unroll
      for (int r4 = 0; r4 < 4; ++r4) {
        int co4 = cb + wco * 64 + i * 32 + 8 * r4 + 4 * hh;
        if (MODE == 1) {
          float4 bv;
          bv.x = (co4 + 0 < CoReal) ? bias[co4 + 0] : 0.f;
          bv.y = (co4 + 1 < CoReal) ? bias[co4 + 1] : 0.f;
          bv.z = (co4 + 2 < CoReal) ? bias[co4 + 2] : 0.f;
          bv.w = (co4 + 3 < CoReal) ? bias[co4 + 3] : 0.f;
          biasv[i][r4] = bv;
        } else {
          biasv[i][r4] = *(const float4*)(bias + co4);
        }
      }
  }

#pragma unroll
  for (int j = 0; j < 4; ++j) {
    const int s = wsp * 128 + j * 32 + l31;
    if constexpr (MODE == 0 || MODE == 1) {
      const int pp = sp0 + s;
      const int hp = pp / PW, wp_ = pp - (pp / PW) * PW;
      const bool inter = ((unsigned)(hp - 1) < 56u) && ((unsigned)(wp_ - 1) < 56u);
      if (!inter) continue;
#pragma unroll
      for (int i = 0; i < 2; ++i) {
#pragma unroll
        for (int r4 = 0; r4 < 4; ++r4) {
          const int co4 = cb + wco * 64 + i * 32 + 8 * r4 + 4 * hh;
          float v0 = acc[i][j][4 * r4 + 0] + biasv[i][r4].x;
          float v1 = acc[i][j][4 * r4 + 1] + biasv[i][r4].y;
          float v2 = acc[i][j][4 * r4 + 2] + biasv[i][r4].z;
          float v3 = acc[i][j][4 * r4 + 3] + biasv[i][r4].w;
          if constexpr (MODE == 0) {
            v0 = fmaxf(v0, 0.f); v1 = fmaxf(v1, 0.f);
            v2 = fmaxf(v2, 0.f); v3 = fmaxf(v3, 0.f);
            ushort4 st;
            st.x = f2bf(v0); st.y = f2bf(v1); st.z = f2bf(v2); st.w = f2bf(v3);
            *(ushort4*)(out_bf + ((size_t)n * NSTR + PBASE + pp) * 256 + co4) = st;
          } else {
            const int pfl = (hp - 1) * WID + (wp_ - 1);
            float* dst = out_f32 + ((size_t)n * HW + pfl) * CoReal;
            if (co4 + 0 < CoReal) dst[co4 + 0] = v0;
            if (co4 + 1 < CoReal) dst[co4 + 1] = v1;
            if (co4 + 2 < CoReal) dst[co4 + 2] = v2;
            if (co4 + 3 < CoReal) dst[co4 + 3] = v3;
          }
        }
      }
    } else {
      const int pfl = sp0 + s;
      if (pfl >= HWl) continue;
#pragma unroll
      for (int i = 0; i < 2; ++i) {
#pragma unroll
        for (int r4 = 0; r4 < 4; ++r4) {
          const int co4 = cb + wco * 64 + i * 32 + 8 * r4 + 4 * hh;
          float v0 = acc[i][j][4 * r4 + 0], v1 = acc[i][j][4 * r4 + 1];
          float v2 = acc[i][j][4 * r4 + 2], v3 = acc[i][j][4 * r4 + 3];
          if constexpr (MODE == 2) {
            v0 += biasv[i][r4].x; v1 += biasv[i][r4].y;
            v2 += biasv[i][r4].z; v3 += biasv[i][r4].w;
          }
          ushort4 st;
          st.x = f2bf(v0); st.y = f2bf(v1); st.z = f2bf(v2); st.w = f2bf(v3);
          if constexpr (MODE == 2) {
            const int h56 = pfl / WID, w56 = pfl - (pfl / WID) * WID;
            const int pp = (h56 + 1) * PW + (w56 + 1);
            *(ushort4*)(out_bf + ((size_t)n * NSTR + PBASE + pp) * 256 + co4) = st;
          } else {
            *(ushort4*)(out_bf + ((size_t)n * HWl + pfl) * 256 + co4) = st;
          }
        }
      }
    }
  }
}

// ---------- launch ----------
extern "C" void kernel_launch(void* const* d_in, const int* in_sizes, int n_in,
                              void* d_out, int out_size, void* d_ws, size_t ws_size,
                              hipStream_t stream) {
  const float* fm0 = (const float*)d_in[0];
  const float* fm1 = (const float*)d_in[1];
  const float* fm2 = (const float*)d_in[2];
  const float* fm3 = (const float*)d_in[3];
  const float* fuse_w = (const float*)d_in[4];
  const float* fuse_b = (const float*)d_in[5];
  const float* cls_w = (const float*)d_in[6];
  const float* cls_b = (const float*)d_in[7];
  const float* cls_hw = (const float*)d_in[8];
  const float* cls_hb = (const float*)d_in[9];
  const float* reg_w = (const float*)d_in[10];
  const float* reg_b = (const float*)d_in[11];
  const float* reg_hw = (const float*)d_in[12];
  const float* reg_hb = (const float*)d_in[13];
  float* out = (float*)d_out;

  const size_t REG_OFF = (size_t)NB * HW * 9 * 10;           // 4,515,840
  const size_t ANC_OFF = REG_OFF + (size_t)NB * HW * 9 * 4;  // 6,322,176

  char* ws = (char*)d_ws;
  const size_t ACTP_B = (size_t)NB * NSTR * 256 * 2;  // 28,835,840
  const size_t WL_B = (size_t)9 * 256 * 256 * 2;      // 1,179,648

  char* wp = ws;
  unsigned short* actA = (unsigned short*)wp;   wp += ACTP_B;
  unsigned short* actB = (unsigned short*)wp;   wp += ACTP_B;
  unsigned short* fusedB = (unsigned short*)wp; wp += ACTP_B;
  unsigned short* fm0n = (unsigned short*)wp;   wp += (size_t)NB * HW * 256 * 2;
  unsigned short* fm1n = (unsigned short*)wp;   wp += (size_t)NB * 784 * 256 * 2;
  unsigned short* fm2n = (unsigned short*)wp;   wp += (size_t)NB * 196 * 256 * 2;
  unsigned short* fm3n = (unsigned short*)wp;   wp += (size_t)NB * 49 * 256 * 2;
  unsigned short* y1 = (unsigned short*)wp;     wp += (size_t)NB * 784 * 256 * 2;
  unsigned short* y2 = (unsigned short*)wp;     wp += (size_t)NB * 196 * 256 * 2;
  unsigned short* y3 = (unsigned short*)wp;     wp += (size_t)NB * 49 * 256 * 2;
  unsigned short* Wfuse = (unsigned short*)wp;  wp += (size_t)256 * 1024 * 2;
  unsigned short* Wsub[8];
  for (int i = 0; i < 8; i++) { Wsub[i] = (unsigned short*)wp; wp += WL_B; }
  unsigned short* Wch = (unsigned short*)wp;    wp += (size_t)9 * 128 * 256 * 2;
  unsigned short* Wrh = (unsigned short*)wp;    wp += (size_t)9 * 128 * 256 * 2;

  // zero activation buffers (borders/junk must be 0; interiors rewritten each layer)
  hipMemsetAsync(actA, 0, ACTP_B, stream);
  hipMemsetAsync(actB, 0, ACTP_B, stream);
  hipMemsetAsync(fusedB, 0, ACTP_B, stream);

  anchors_k<<<dim3((HW * 9 + 255) / 256), 256, 0, stream>>>(out + ANC_OFF);
  fuse_w_k<<<dim3(1024), 256, 0, stream>>>(fuse_w, Wfuse);
  for (int i = 0; i < 4; i++) {
    conv_w_k<<<dim3(9 * 256), 256, 0, stream>>>(cls_w + (size_t)i * 589824, Wsub[i], 256, 256);
    conv_w_k<<<dim3(9 * 256), 256, 0, stream>>>(reg_w + (size_t)i * 589824, Wsub[4 + i], 256, 256);
  }
  conv_w_k<<<dim3(9 * 128), 256, 0, stream>>>(cls_hw, Wch, 90, 128);
  conv_w_k<<<dim3(9 * 128), 256, 0, stream>>>(reg_hw, Wrh, 36, 128);

  // NCHW -> NHWC bf16
  nchw2nhwc<<<dim3(49, 4, NB), 256, 0, stream>>>(fm0, fm0n, HW);
  nchw2nhwc<<<dim3(13, 4, NB), 256, 0, stream>>>(fm1, fm1n, 784);
  nchw2nhwc<<<dim3(4, 4, NB), 256, 0, stream>>>(fm2, fm2n, 196);
  nchw2nhwc<<<dim3(1, 4, NB), 256, 0, stream>>>(fm3, fm3n, 49);

  // fuse path: y0 = W0@fm0 + b  (padded out), y_l = W_l@fm_l (flat), then combine
  conv3<1, 2><<<dim3(13, 2, NB), 256, 0, stream>>>(fm0n, Wfuse, 1024, 0, fuse_b, fusedB, nullptr, 256, HW);
  conv3<1, 3><<<dim3(4, 2, NB), 256, 0, stream>>>(fm1n, Wfuse + 256, 1024, 0, nullptr, y1, nullptr, 256, 784);
  conv3<1, 3><<<dim3(1, 2, NB), 256, 0, stream>>>(fm2n, Wfuse + 512, 1024, 0, nullptr, y2, nullptr, 256, 196);
  conv3<1, 3><<<dim3(1, 2, NB), 256, 0, stream>>>(fm3n, Wfuse + 768, 1024, 0, nullptr, y3, nullptr, 256, 49);
  combine_k<<<dim3((NB * HW * 32) / 256), 256, 0, stream>>>(fusedB, y1, y2, y3);

  // cls subnet
  conv3<9, 0><<<dim3(13, 2, NB), 256, 0, stream>>>(fusedB, Wsub[0], 256, 65536, cls_b + 0, actA, nullptr, 256, 0);
  conv3<9, 0><<<dim3(13, 2, NB), 256, 0, stream>>>(actA, Wsub[1], 256, 65536, cls_b + 256, actB, nullptr, 256, 0);
  conv3<9, 0><<<dim3(13, 2, NB), 256, 0, stream>>>(actB, Wsub[2], 256, 65536, cls_b + 512, actA, nullptr, 256, 0);
  conv3<9, 0><<<dim3(13, 2, NB), 256, 0, stream>>>(actA, Wsub[3], 256, 65536, cls_b + 768, actB, nullptr, 256, 0);
  conv3<9, 1><<<dim3(13, 1, NB), 256, 0, stream>>>(actB, Wch, 256, 32768, cls_hb, nullptr, out, 90, 0);

  // reg subnet
  conv3<9, 0><<<dim3(13, 2, NB), 256, 0, stream>>>(fusedB, Wsub[4], 256, 65536, reg_b + 0, actA, nullptr, 256, 0);
  conv3<9, 0><<<dim3(13, 2, NB), 256, 0, stream>>>(actA, Wsub[5], 256, 65536, reg_b + 256, actB, nullptr, 256, 0);
  conv3<9, 0><<<dim3(13, 2, NB), 256, 0, stream>>>(actB, Wsub[6], 256, 65536, reg_b + 512, actA, nullptr, 256, 0);
  conv3<9, 0><<<dim3(13, 2, NB), 256, 0, stream>>>(actA, Wsub[7], 256, 65536, reg_b + 768, actB, nullptr, 256, 0);
  conv3<9, 1><<<dim3(13, 1, NB), 256, 0, stream>>>(actB, Wrh, 256, 32768, reg_hb, nullptr, out + REG_OFF, 36, 0);
}

// Round 5
// 982.311 us; speedup vs baseline: 4.4341x; 1.0147x over previous
//
#include <hip/hip_runtime.h>

typedef __attribute__((ext_vector_type(8))) short bf16x8;
typedef __attribute__((ext_vector_type(4))) float f32x4;
typedef __attribute__((ext_vector_type(16))) float f32x16;

#define NB 16
#define WID 56
#define HW 3136    // 56*56
#define PW 58      // padded row width
#define NSTR 3520  // per-n position stride in padded act buffers
#define PBASE 64   // plane offset (positions) within per-n region
#define HALO 59    // max |dy*58+dx|

// ---------- helpers ----------
__device__ __forceinline__ unsigned short f2bf(float f) {
  unsigned u = __float_as_uint(f);
  u = (u + 0x7fffu + ((u >> 16) & 1u)) >> 16;
  return (unsigned short)u;
}
__device__ __forceinline__ float bf2f(unsigned short u) {
  return __uint_as_float(((unsigned)u) << 16);
}

// ---------- anchors ----------
__constant__ float cAW[9] = {11.f, 23.f, 45.f, 8.f, 16.f, 32.f, 6.f, 11.f, 23.f};
__constant__ float cAH[9] = {6.f, 11.f, 23.f, 8.f, 16.f, 32.f, 11.f, 23.f, 45.f};

__global__ void anchors_k(float* __restrict__ out) {
  int idx = blockIdx.x * 256 + threadIdx.x;
  if (idx >= HW * 9) return;
  int g = idx / 9, a = idx - g * 9;
  int y = g / WID, x = g - y * WID;
  float gx = x * 4.f, gy = y * 4.f;
  float4 v = make_float4(gx - cAW[a], gy - cAH[a], gx + cAW[a], gy + cAH[a]);
  *(float4*)(out + (size_t)idx * 4) = v;
}

// ---------- weight conversion ----------
// fuse_w (256,1024) fp32 -> bf16 same layout
__global__ void fuse_w_k(const float* __restrict__ in, unsigned short* __restrict__ out) {
  int idx = blockIdx.x * 256 + threadIdx.x;
  if (idx >= 256 * 1024) return;
  out[idx] = f2bf(in[idx]);
}

// conv w (Co,256,3,3) fp32 -> bf16 [t][coPad][ci=256]
__global__ void conv_w_k(const float* __restrict__ in, unsigned short* __restrict__ out,
                         int Co, int CoPad) {
  int idx = blockIdx.x * 256 + threadIdx.x;
  int total = CoPad * 256 * 9;
  if (idx >= total) return;
  int ci = idx & 255;
  int co = (idx >> 8) % CoPad;
  int t = idx / (CoPad * 256);
  float v = (co < Co) ? in[(co * 256 + ci) * 9 + t] : 0.f;
  out[idx] = f2bf(v);
}

// ---------- NCHW fp32 -> NHWC bf16 transpose ----------
__global__ __launch_bounds__(256) void nchw2nhwc(const float* __restrict__ in,
                                                 unsigned short* __restrict__ outb, int HWl) {
  __shared__ float tile[64][65];
  const int pb = blockIdx.x * 64;
  const int cb = blockIdx.y * 64;
  const int n = blockIdx.z;
  const int t = threadIdx.x;
  const int pl = t & 63;
#pragma unroll
  for (int i = 0; i < 16; ++i) {
    int cl = i * 4 + (t >> 6);
    int p = pb + pl;
    if (p >= HWl) p = HWl - 1;
    tile[cl][pl] = in[((size_t)n * 256 + cb + cl) * HWl + p];
  }
  __syncthreads();
  const int pl2 = t >> 4;         // 0..15
  const int cl2 = (t & 15) * 4;   // 0..60
#pragma unroll
  for (int i = 0; i < 4; ++i) {
    int pp = pb + i * 16 + pl2;
    if (pp < HWl) {
      ushort4 st;
      st.x = f2bf(tile[cl2 + 0][i * 16 + pl2]);
      st.y = f2bf(tile[cl2 + 1][i * 16 + pl2]);
      st.z = f2bf(tile[cl2 + 2][i * 16 + pl2]);
      st.w = f2bf(tile[cl2 + 3][i * 16 + pl2]);
      *(ushort4*)(outb + ((size_t)n * HWl + pp) * 256 + cb + cl2) = st;
    }
  }
}

// ---------- upsample-add combine: fused(padded) += U(y1)+U(y2)+U(y3) ----------
__device__ __forceinline__ void add_up(float* v, const unsigned short* __restrict__ y,
                                       int n, int S, float r, int h, int w, int c8) {
  float fy = ((float)h + 0.5f) * r - 0.5f;
  float fx = ((float)w + 0.5f) * r - 0.5f;
  float fyf = floorf(fy), fxf = floorf(fx);
  float ty = fy - fyf, tx = fx - fxf;
  int y0 = (int)fyf, x0 = (int)fxf;
  int y0c = min(max(y0, 0), S - 1), y1c = min(max(y0 + 1, 0), S - 1);
  int x0c = min(max(x0, 0), S - 1), x1c = min(max(x0 + 1, 0), S - 1);
  const unsigned short* b = y + (size_t)n * S * S * 256;
  bf16x8 a00 = *(const bf16x8*)(b + ((size_t)(y0c * S + x0c)) * 256 + c8);
  bf16x8 a01 = *(const bf16x8*)(b + ((size_t)(y0c * S + x1c)) * 256 + c8);
  bf16x8 a10 = *(const bf16x8*)(b + ((size_t)(y1c * S + x0c)) * 256 + c8);
  bf16x8 a11 = *(const bf16x8*)(b + ((size_t)(y1c * S + x1c)) * 256 + c8);
  float w00 = (1.f - ty) * (1.f - tx), w01 = (1.f - ty) * tx;
  float w10 = ty * (1.f - tx), w11 = ty * tx;
#pragma unroll
  for (int e = 0; e < 8; ++e) {
    v[e] += w00 * bf2f((unsigned short)a00[e]) + w01 * bf2f((unsigned short)a01[e]) +
            w10 * bf2f((unsigned short)a10[e]) + w11 * bf2f((unsigned short)a11[e]);
  }
}

__global__ __launch_bounds__(256) void combine_k(unsigned short* __restrict__ fused,
                                                 const unsigned short* __restrict__ y1,
                                                 const unsigned short* __restrict__ y2,
                                                 const unsigned short* __restrict__ y3) {
  int idx = blockIdx.x * 256 + threadIdx.x;  // [n][3136][32 octets]
  int c8 = (idx & 31) * 8;
  int np = idx >> 5;
  int p = np % HW;
  int n = np / HW;
  int h = p / WID, w = p - h * WID;
  size_t po = ((size_t)n * NSTR + PBASE + (h + 1) * PW + (w + 1)) * 256 + c8;
  bf16x8 f0 = *(bf16x8*)(fused + po);
  float v[8];
#pragma unroll
  for (int e = 0; e < 8; ++e) v[e] = bf2f((unsigned short)f0[e]);
  add_up(v, y1, n, 28, 0.5f, h, w, c8);
  add_up(v, y2, n, 14, 0.25f, h, w, c8);
  add_up(v, y3, n, 7, 0.125f, h, w, c8);
  bf16x8 st;
#pragma unroll
  for (int e = 0; e < 8; ++e) st[e] = (short)f2bf(v[e]);
  *(bf16x8*)(fused + po) = st;
}

// ---------- conv3: implicit GEMM, 32x32x16 MFMA, W+act both in LDS ----------
// Block: 128co x 256sp, 4 waves (wsp = wv&1 two sp-halves of 128, wco = wv>>1 two co-halves of 64).
// Wave tile: 64co x 128sp = 2 co-frags x 4 sp-frags of 32.
// act LDS: [8 k-slots][384 pos][16B] at 0 (48KB). W LDS: 2 x [8 slots][128 co][16B] at 49152.
// K-chain: 4 ci-quarters(64) x NTAPS taps x 4 k16.
// Pipeline: counted vmcnt(4) keeps next-tap W-loads in flight across both raw barriers
// (2-buffer W, distance-1 prefetch; end-of-tap barrier provides the WAR separation).
// MODE 0: padded-in -> padded-out bf16, bias+relu (subnet)
// MODE 1: padded-in -> flat fp32 out, co<CoReal, bias (heads)
// MODE 2: flat-in[HWl][256] -> padded-out bf16, bias (fuse level 0)
// MODE 3: flat-in[HWl][256] -> flat-out bf16 [HWl][256], no bias (fuse levels 1-3)
template <int NTAPS, int MODE>
__global__ __launch_bounds__(256, 2) void conv3(
    const unsigned short* __restrict__ act, const unsigned short* __restrict__ wt,
    int wrs, int wts, const float* __restrict__ bias,
    unsigned short* __restrict__ out_bf, float* __restrict__ out_f32,
    int CoReal, int HWl) {
  __shared__ __align__(16) char smem[48 * 1024 + 2 * 16 * 1024];
  const int n = blockIdx.z;
  const int cb = blockIdx.y * 128;
  const int sp0 = blockIdx.x * 256;
  const int tid = threadIdx.x;
  const int lane = tid & 63;
  const int wv = tid >> 6;
  const int wsp = wv & 1;
  const int wco = wv >> 1;
  const int l31 = lane & 31;
  const int hh = lane >> 5;

  f32x16 acc[2][4];
#pragma unroll
  for (int i = 0; i < 2; ++i)
#pragma unroll
    for (int j = 0; j < 4; ++j)
#pragma unroll
      for (int r = 0; r < 16; ++r) acc[i][j][r] = 0.f;

  // ---- staging lambdas ----
  auto stage_act = [&](int q) {
    if constexpr (MODE <= 1) {
      const unsigned short* base =
          act + ((size_t)n * NSTR + PBASE + sp0 - HALO) * 256 + q * 64;
#pragma unroll
      for (int i = 0; i < 12; ++i) {
        int G = i * 256 + tid;
        int s = G / 384;
        int pos = G - s * 384;
        const unsigned short* g = base + (size_t)pos * 256 + s * 8;
        __builtin_amdgcn_global_load_lds((const __attribute__((address_space(1))) void*)g,
                                         (__attribute__((address_space(3))) void*)(smem + (size_t)G * 16),
                                         16, 0, 0);
      }
    } else {
#pragma unroll
      for (int i = 0; i < 8; ++i) {
        int G = i * 256 + tid;
        int s = G >> 8;
        int pos = G & 255;
        int row = sp0 + pos;
        if (row > HWl - 1) row = HWl - 1;
        const unsigned short* g = act + ((size_t)n * HWl + row) * 256 + q * 64 + s * 8;
        __builtin_amdgcn_global_load_lds((const __attribute__((address_space(1))) void*)g,
                                         (__attribute__((address_space(3))) void*)(smem + (size_t)s * 6144 + pos * 16),
                                         16, 0, 0);
      }
    }
  };

  auto stage_w = [&](int pair, int bufsel) {
    int q = pair / NTAPS;
    int t = pair - q * NTAPS;
    const unsigned short* base = wt + (size_t)t * wts + (size_t)cb * wrs + q * 64;
    char* wb = smem + 49152 + bufsel * 16384;
#pragma unroll
    for (int i = 0; i < 4; ++i) {
      int G = i * 256 + tid;
      int s = G >> 7, co = G & 127;
      const unsigned short* g = base + (size_t)co * wrs + s * 8;
      __builtin_amdgcn_global_load_lds((const __attribute__((address_space(1))) void*)g,
                                       (__attribute__((address_space(3))) void*)(wb + (size_t)G * 16),
                                       16, 0, 0);
    }
  };

  constexpr int TP = 4 * NTAPS;

  stage_act(0);
  stage_w(0, 0);
  asm volatile("s_waitcnt vmcnt(0)" ::: "memory");
  __builtin_amdgcn_s_barrier();

  const int abase0 = 49152 + (wco * 64 + l31) * 16 + hh * 2048;
  const int bpos0 = wsp * 128 + l31;

  int p = 0;
#pragma unroll 1
  for (int q = 0; q < 4; ++q) {
#pragma unroll 1
    for (int t = 0; t < NTAPS; ++t, ++p) {
      if (p + 1 < TP) {
        stage_w(p + 1, (p + 1) & 1);
        asm volatile("s_waitcnt vmcnt(4)" ::: "memory");  // W(p)+act drained; 4 newest in flight
      } else {
        asm volatile("s_waitcnt vmcnt(0)" ::: "memory");
      }
      __builtin_amdgcn_s_barrier();  // barrier1: W(p) visible to all waves

      const int tapadd = (NTAPS == 9) ? ((t / 3) * PW + (t - (t / 3) * 3)) : 0;
      const char* wbuf = smem + (p & 1) * 16384;
      const int bb = (bpos0 + tapadd) * 16 + hh * 6144;
      __builtin_amdgcn_s_setprio(1);
#pragma unroll
      for (int kk = 0; kk < 4; ++kk) {
        bf16x8 a0 = *(const bf16x8*)(wbuf + abase0 + kk * 4096);
        bf16x8 a1 = *(const bf16x8*)(wbuf + abase0 + 512 + kk * 4096);
        bf16x8 b0 = *(const bf16x8*)(smem + bb + kk * 12288);
        bf16x8 b1 = *(const bf16x8*)(smem + bb + 512 + kk * 12288);
        bf16x8 b2 = *(const bf16x8*)(smem + bb + 1024 + kk * 12288);
        bf16x8 b3 = *(const bf16x8*)(smem + bb + 1536 + kk * 12288);
        acc[0][0] = __builtin_amdgcn_mfma_f32_32x32x16_bf16(a0, b0, acc[0][0], 0, 0, 0);
        acc[0][1] = __builtin_amdgcn_mfma_f32_32x32x16_bf16(a0, b1, acc[0][1], 0, 0, 0);
        acc[0][2] = __builtin_amdgcn_mfma_f32_32x32x16_bf16(a0, b2, acc[0][2], 0, 0, 0);
        acc[0][3] = __builtin_amdgcn_mfma_f32_32x32x16_bf16(a0, b3, acc[0][3], 0, 0, 0);
        acc[1][0] = __builtin_amdgcn_mfma_f32_32x32x16_bf16(a1, b0, acc[1][0], 0, 0, 0);
        acc[1][1] = __builtin_amdgcn_mfma_f32_32x32x16_bf16(a1, b1, acc[1][1], 0, 0, 0);
        acc[1][2] = __builtin_amdgcn_mfma_f32_32x32x16_bf16(a1, b2, acc[1][2], 0, 0, 0);
        acc[1][3] = __builtin_amdgcn_mfma_f32_32x32x16_bf16(a1, b3, acc[1][3], 0, 0, 0);
      }
      __builtin_amdgcn_s_setprio(0);
      asm volatile("s_waitcnt lgkmcnt(0)" ::: "memory");  // all ds_reads of tap p retired
      __builtin_amdgcn_s_barrier();  // barrier2: safe to overwrite W buf (p+1)&1 / act
      if (t == NTAPS - 1 && q < 3) stage_act(q + 1);
    }
  }

  // ---- epilogue: D col = lane&31 (sp), row = (r&3)+8*(r>>2)+4*(lane>>5) (co) ----
  float4 biasv[2][4];
  if constexpr (MODE != 3) {
#pragma unroll
    for (int i = 0; i < 2; ++i)
#pragma unroll
      for (int r4 = 0; r4 < 4; ++r4) {
        int co4 = cb + wco * 64 + i * 32 + 8 * r4 + 4 * hh;
        if (MODE == 1) {
          float4 bv;
          bv.x = (co4 + 0 < CoReal) ? bias[co4 + 0] : 0.f;
          bv.y = (co4 + 1 < CoReal) ? bias[co4 + 1] : 0.f;
          bv.z = (co4 + 2 < CoReal) ? bias[co4 + 2] : 0.f;
          bv.w = (co4 + 3 < CoReal) ? bias[co4 + 3] : 0.f;
          biasv[i][r4] = bv;
        } else {
          biasv[i][r4] = *(const float4*)(bias + co4);
        }
      }
  }

#pragma unroll
  for (int j = 0; j < 4; ++j) {
    const int s = wsp * 128 + j * 32 + l31;
    if constexpr (MODE == 0 || MODE == 1) {
      const int pp = sp0 + s;
      const int hp = pp / PW, wp_ = pp - (pp / PW) * PW;
      const bool inter = ((unsigned)(hp - 1) < 56u) && ((unsigned)(wp_ - 1) < 56u);
      if (!inter) continue;
#pragma unroll
      for (int i = 0; i < 2; ++i) {
#pragma unroll
        for (int r4 = 0; r4 < 4; ++r4) {
          const int co4 = cb + wco * 64 + i * 32 + 8 * r4 + 4 * hh;
          float v0 = acc[i][j][4 * r4 + 0] + biasv[i][r4].x;
          float v1 = acc[i][j][4 * r4 + 1] + biasv[i][r4].y;
          float v2 = acc[i][j][4 * r4 + 2] + biasv[i][r4].z;
          float v3 = acc[i][j][4 * r4 + 3] + biasv[i][r4].w;
          if constexpr (MODE == 0) {
            v0 = fmaxf(v0, 0.f); v1 = fmaxf(v1, 0.f);
            v2 = fmaxf(v2, 0.f); v3 = fmaxf(v3, 0.f);
            ushort4 st;
            st.x = f2bf(v0); st.y = f2bf(v1); st.z = f2bf(v2); st.w = f2bf(v3);
            *(ushort4*)(out_bf + ((size_t)n * NSTR + PBASE + pp) * 256 + co4) = st;
          } else {
            const int pfl = (hp - 1) * WID + (wp_ - 1);
            float* dst = out_f32 + ((size_t)n * HW + pfl) * CoReal;
            if (co4 + 0 < CoReal) dst[co4 + 0] = v0;
            if (co4 + 1 < CoReal) dst[co4 + 1] = v1;
            if (co4 + 2 < CoReal) dst[co4 + 2] = v2;
            if (co4 + 3 < CoReal) dst[co4 + 3] = v3;
          }
        }
      }
    } else {
      const int pfl = sp0 + s;
      if (pfl >= HWl) continue;
#pragma unroll
      for (int i = 0; i < 2; ++i) {
#pragma unroll
        for (int r4 = 0; r4 < 4; ++r4) {
          const int co4 = cb + wco * 64 + i * 32 + 8 * r4 + 4 * hh;
          float v0 = acc[i][j][4 * r4 + 0], v1 = acc[i][j][4 * r4 + 1];
          float v2 = acc[i][j][4 * r4 + 2], v3 = acc[i][j][4 * r4 + 3];
          if constexpr (MODE == 2) {
            v0 += biasv[i][r4].x; v1 += biasv[i][r4].y;
            v2 += biasv[i][r4].z; v3 += biasv[i][r4].w;
          }
          ushort4 st;
          st.x = f2bf(v0); st.y = f2bf(v1); st.z = f2bf(v2); st.w = f2bf(v3);
          if constexpr (MODE == 2) {
            const int h56 = pfl / WID, w56 = pfl - (pfl / WID) * WID;
            const int pp = (h56 + 1) * PW + (w56 + 1);
            *(ushort4*)(out_bf + ((size_t)n * NSTR + PBASE + pp) * 256 + co4) = st;
          } else {
            *(ushort4*)(out_bf + ((size_t)n * HWl + pfl) * 256 + co4) = st;
          }
        }
      }
    }
  }
}

// ---------- launch ----------
extern "C" void kernel_launch(void* const* d_in, const int* in_sizes, int n_in,
                              void* d_out, int out_size, void* d_ws, size_t ws_size,
                              hipStream_t stream) {
  const float* fm0 = (const float*)d_in[0];
  const float* fm1 = (const float*)d_in[1];
  const float* fm2 = (const float*)d_in[2];
  const float* fm3 = (const float*)d_in[3];
  const float* fuse_w = (const float*)d_in[4];
  const float* fuse_b = (const float*)d_in[5];
  const float* cls_w = (const float*)d_in[6];
  const float* cls_b = (const float*)d_in[7];
  const float* cls_hw = (const float*)d_in[8];
  const float* cls_hb = (const float*)d_in[9];
  const float* reg_w = (const float*)d_in[10];
  const float* reg_b = (const float*)d_in[11];
  const float* reg_hw = (const float*)d_in[12];
  const float* reg_hb = (const float*)d_in[13];
  float* out = (float*)d_out;

  const size_t REG_OFF = (size_t)NB * HW * 9 * 10;           // 4,515,840
  const size_t ANC_OFF = REG_OFF + (size_t)NB * HW * 9 * 4;  // 6,322,176

  char* ws = (char*)d_ws;
  const size_t ACTP_B = (size_t)NB * NSTR * 256 * 2;  // 28,835,840
  const size_t WL_B = (size_t)9 * 256 * 256 * 2;      // 1,179,648

  char* wp = ws;
  unsigned short* actA = (unsigned short*)wp;   wp += ACTP_B;
  unsigned short* actB = (unsigned short*)wp;   wp += ACTP_B;
  unsigned short* fusedB = (unsigned short*)wp; wp += ACTP_B;
  unsigned short* fm0n = (unsigned short*)wp;   wp += (size_t)NB * HW * 256 * 2;
  unsigned short* fm1n = (unsigned short*)wp;   wp += (size_t)NB * 784 * 256 * 2;
  unsigned short* fm2n = (unsigned short*)wp;   wp += (size_t)NB * 196 * 256 * 2;
  unsigned short* fm3n = (unsigned short*)wp;   wp += (size_t)NB * 49 * 256 * 2;
  unsigned short* y1 = (unsigned short*)wp;     wp += (size_t)NB * 784 * 256 * 2;
  unsigned short* y2 = (unsigned short*)wp;     wp += (size_t)NB * 196 * 256 * 2;
  unsigned short* y3 = (unsigned short*)wp;     wp += (size_t)NB * 49 * 256 * 2;
  unsigned short* Wfuse = (unsigned short*)wp;  wp += (size_t)256 * 1024 * 2;
  unsigned short* Wsub[8];
  for (int i = 0; i < 8; i++) { Wsub[i] = (unsigned short*)wp; wp += WL_B; }
  unsigned short* Wch = (unsigned short*)wp;    wp += (size_t)9 * 128 * 256 * 2;
  unsigned short* Wrh = (unsigned short*)wp;    wp += (size_t)9 * 128 * 256 * 2;

  // zero activation buffers (borders/junk must be 0; interiors rewritten each layer)
  hipMemsetAsync(actA, 0, ACTP_B, stream);
  hipMemsetAsync(actB, 0, ACTP_B, stream);
  hipMemsetAsync(fusedB, 0, ACTP_B, stream);

  anchors_k<<<dim3((HW * 9 + 255) / 256), 256, 0, stream>>>(out + ANC_OFF);
  fuse_w_k<<<dim3(1024), 256, 0, stream>>>(fuse_w, Wfuse);
  for (int i = 0; i < 4; i++) {
    conv_w_k<<<dim3(9 * 256), 256, 0, stream>>>(cls_w + (size_t)i * 589824, Wsub[i], 256, 256);
    conv_w_k<<<dim3(9 * 256), 256, 0, stream>>>(reg_w + (size_t)i * 589824, Wsub[4 + i], 256, 256);
  }
  conv_w_k<<<dim3(9 * 128), 256, 0, stream>>>(cls_hw, Wch, 90, 128);
  conv_w_k<<<dim3(9 * 128), 256, 0, stream>>>(reg_hw, Wrh, 36, 128);

  // NCHW -> NHWC bf16
  nchw2nhwc<<<dim3(49, 4, NB), 256, 0, stream>>>(fm0, fm0n, HW);
  nchw2nhwc<<<dim3(13, 4, NB), 256, 0, stream>>>(fm1, fm1n, 784);
  nchw2nhwc<<<dim3(4, 4, NB), 256, 0, stream>>>(fm2, fm2n, 196);
  nchw2nhwc<<<dim3(1, 4, NB), 256, 0, stream>>>(fm3, fm3n, 49);

  // fuse path: y0 = W0@fm0 + b  (padded out), y_l = W_l@fm_l (flat), then combine
  conv3<1, 2><<<dim3(13, 2, NB), 256, 0, stream>>>(fm0n, Wfuse, 1024, 0, fuse_b, fusedB, nullptr, 256, HW);
  conv3<1, 3><<<dim3(4, 2, NB), 256, 0, stream>>>(fm1n, Wfuse + 256, 1024, 0, nullptr, y1, nullptr, 256, 784);
  conv3<1, 3><<<dim3(1, 2, NB), 256, 0, stream>>>(fm2n, Wfuse + 512, 1024, 0, nullptr, y2, nullptr, 256, 196);
  conv3<1, 3><<<dim3(1, 2, NB), 256, 0, stream>>>(fm3n, Wfuse + 768, 1024, 0, nullptr, y3, nullptr, 256, 49);
  combine_k<<<dim3((NB * HW * 32) / 256), 256, 0, stream>>>(fusedB, y1, y2, y3);

  // cls subnet
  conv3<9, 0><<<dim3(13, 2, NB), 256, 0, stream>>>(fusedB, Wsub[0], 256, 65536, cls_b + 0, actA, nullptr, 256, 0);
  conv3<9, 0><<<dim3(13, 2, NB), 256, 0, stream>>>(actA, Wsub[1], 256, 65536, cls_b + 256, actB, nullptr, 256, 0);
  conv3<9, 0><<<dim3(13, 2, NB), 256, 0, stream>>>(actB, Wsub[2], 256, 65536, cls_b + 512, actA, nullptr, 256, 0);
  conv3<9, 0><<<dim3(13, 2, NB), 256, 0, stream>>>(actA, Wsub[3], 256, 65536, cls_b + 768, actB, nullptr, 256, 0);
  conv3<9, 1><<<dim3(13, 1, NB), 256, 0, stream>>>(actB, Wch, 256, 32768, cls_hb, nullptr, out, 90, 0);

  // reg subnet
  conv3<9, 0><<<dim3(13, 2, NB), 256, 0, stream>>>(fusedB, Wsub[4], 256, 65536, reg_b + 0, actA, nullptr, 256, 0);
  conv3<9, 0><<<dim3(13, 2, NB), 256, 0, stream>>>(actA, Wsub[5], 256, 65536, reg_b + 256, actB, nullptr, 256, 0);
  conv3<9, 0><<<dim3(13, 2, NB), 256, 0, stream>>>(actB, Wsub[6], 256, 65536, reg_b + 512, actA, nullptr, 256, 0);
  conv3<9, 0><<<dim3(13, 2, NB), 256, 0, stream>>>(actA, Wsub[7], 256, 65536, reg_b + 768, actB, nullptr, 256, 0);
  conv3<9, 1><<<dim3(13, 1, NB), 256, 0, stream>>>(actB, Wrh, 256, 32768, reg_hb, nullptr, out + REG_OFF, 36, 0);
}